// Round 9
// baseline (219.762 us; speedup 1.0000x reference)
//
#include <hip/hip_runtime.h>

typedef __bf16 bf16x8 __attribute__((ext_vector_type(8)));
typedef float  f32x4  __attribute__((ext_vector_type(4)));

#define LOG2E 1.4426950408889634f

static __device__ __forceinline__ float fexp2(float x) { return __builtin_amdgcn_exp2f(x); }
static __device__ __forceinline__ float frcp(float x)  { return __builtin_amdgcn_rcpf(x); }
static __device__ __forceinline__ float fsigmoid(float x) { return frcp(1.0f + fexp2(-LOG2E * x)); }
static __device__ __forceinline__ float ftanh(float x)    { return 2.0f * frcp(1.0f + fexp2(-2.0f * LOG2E * x)) - 1.0f; }

// ---------------------------------------------------------------------------
// Prep: pack 4 [512x512] fp32 weights into bf16 16x16x32-B-fragment order.
// Wp[(((g*32+cn)*16+ks)*64 + lane)*8 + e] = W_g[cn*16+(lane&15)][ks*32+(lane>>4)*8+e]
// ---------------------------------------------------------------------------
__global__ __launch_bounds__(256) void wpack(const float* __restrict__ Wf,
                                             const float* __restrict__ Wi,
                                             const float* __restrict__ Wg,
                                             const float* __restrict__ Wo,
                                             __bf16* __restrict__ Wp)
{
    int idx = blockIdx.x * 256 + threadIdx.x;      // [0, 131072)
    int kg  = idx & 63;                            // k-group of 8
    int j   = (idx >> 6) & 511;                    // weight row = output col
    int g   = idx >> 15;
    const float* src = (g == 0) ? Wf : (g == 1) ? Wi : (g == 2) ? Wg : Wo;
    const float4* s4 = (const float4*)(src + j * 512 + kg * 8);
    float4 v0 = s4[0], v1 = s4[1];
    bf16x8 o;
    o[0] = (__bf16)v0.x; o[1] = (__bf16)v0.y; o[2] = (__bf16)v0.z; o[3] = (__bf16)v0.w;
    o[4] = (__bf16)v1.x; o[5] = (__bf16)v1.y; o[6] = (__bf16)v1.z; o[7] = (__bf16)v1.w;
    int cn = j >> 4;                               // 16-col group
    int ks = kg >> 2;                              // K=32 step
    int lt = (j & 15) + (kg & 3) * 16;             // lane slot
    size_t dst = ((size_t)(((g * 32 + cn) * 16 + ks) * 64 + lt)) * 8;
    *(bf16x8*)(Wp + dst) = o;
}

// ---------------------------------------------------------------------------
// Main fused kernel. Block: 1024 thr (16 waves), BM=128, LDS = 128K z + 32K xchg.
// GATE-SPLIT twins: wave wv and wv+8 cover the SAME 128 rows x 16 cols;
// rh=wv>>3 selects gates {F,I} (rh=0) or {G,O} (rh=1). acc = 8m x 2g x 4 = 64.
// B traffic: 2 x 1KB per wave per ks, zero duplication -> 32 KB/ks/CU (L2-safe).
// c,h combine via 32 KB LDS exchange between twins after each ci.
// ---------------------------------------------------------------------------
__global__ __launch_bounds__(1024, 4) void lstm_main(
    const float* __restrict__ xin, const float* __restrict__ stm,
    const __bf16* __restrict__ Wp,
    const float* __restrict__ bfv, const float* __restrict__ biv,
    const float* __restrict__ bgv, const float* __restrict__ bov,
    float* __restrict__ out)
{
    __shared__ unsigned char zs[131072];           // 128 rows x 512 k, bf16, frag order
    __shared__ unsigned char xbuf[32768];          // twin exchange: [pair][dir][gate][lane][16B]
    const int tid  = threadIdx.x;
    const int lane = tid & 63;
    const int wv   = tid >> 6;                     // 0..15
    const int cn8  = wv & 7;                       // column group within ci (pair id)
    const int rh   = wv >> 3;                      // 0: gates F,I   1: gates G,O
    const int l15  = lane & 15;
    const int lq   = lane >> 4;                    // 0..3
    const int row0 = blockIdx.x * 128;

    // ---- phase 0: z = x + stm -> bf16 -> LDS in frag order (verified layout) ----
    {
        const float* xb = xin + (size_t)row0 * 512;
        const float* sb = stm + (size_t)row0 * 512;
        #pragma unroll
        for (int it = 0; it < 8; ++it) {
            int idx = it * 1024 + tid;             // [0, 8192): 128 rows x 64 kgroups
            int row = idx >> 6;
            int kg  = idx & 63;
            const float4* x4 = (const float4*)(xb + row * 512 + kg * 8);
            const float4* s4 = (const float4*)(sb + row * 512 + kg * 8);
            float4 a0 = x4[0], a1 = x4[1];
            float4 b0 = s4[0], b1 = s4[1];
            bf16x8 p;
            p[0] = (__bf16)(a0.x + b0.x); p[1] = (__bf16)(a0.y + b0.y);
            p[2] = (__bf16)(a0.z + b0.z); p[3] = (__bf16)(a0.w + b0.w);
            p[4] = (__bf16)(a1.x + b1.x); p[5] = (__bf16)(a1.y + b1.y);
            p[6] = (__bf16)(a1.z + b1.z); p[7] = (__bf16)(a1.w + b1.w);
            int rb   = row >> 5;                   // 0..3 chunk (32 KiB each)
            int kk   = kg >> 1;
            int slot = ((row & 31) + (kg & 1) * 32) ^ (kk & 7);
            *(bf16x8*)(zs + rb * 32768 + kk * 1024 + slot * 16) = p;
        }
    }
    __syncthreads();

    // A-read invariants (verified r6 formulas), m = 0..7 over all 128 rows:
    // byte = (m>>1)*32768 + (m&1)*256 + ((s0^kk7)<<4) + ks*2048 + (kkoff<<10)
    const int kkoff = lq >> 1;                     // 0/1
    const int s0    = l15 + (lq & 1) * 32;         // bit4 clear
    const int koffb = kkoff << 10;

    // this wave's two gates: g0 = rh*2, g1 = rh*2+1
    const float* bias_a = rh ? bgv : bfv;
    const float* bias_b = rh ? bov : biv;

    // ---- phase 1: column loop ----
    for (int ci = 0; ci < 4; ++ci) {
        const int cn   = ci * 8 + cn8;             // 16-col group [0,32)
        const int colj = cn * 16 + l15;

        const __bf16* bpA = Wp + ((size_t)(((rh * 2    ) * 32 + cn) * 16)) * 512 + lane * 8;
        const __bf16* bpB = Wp + ((size_t)(((rh * 2 + 1) * 32 + cn) * 16)) * 512 + lane * 8;

        float biasA = bias_a[colj], biasB = bias_b[colj];
        f32x4 acc[8][2];                           // [m][gate] = 64 regs
        #pragma unroll
        for (int m = 0; m < 8; ++m) {
            #pragma unroll
            for (int r = 0; r < 4; ++r) { acc[m][0][r] = biasA; acc[m][1][r] = biasB; }
        }

        #pragma unroll 2
        for (int ks = 0; ks < 16; ++ks) {
            const int kk7 = ((2 * ks) & 7) | kkoff;
            const int t0  = ((s0 ^ kk7) << 4) + ks * 2048 + koffb;
            bf16x8 b0 = *(const bf16x8*)(bpA + ks * 512);
            bf16x8 b1 = *(const bf16x8*)(bpB + ks * 512);
            bf16x8 a[8];
            #pragma unroll
            for (int m = 0; m < 8; ++m)
                a[m] = *(const bf16x8*)(zs + (m >> 1) * 32768 + (m & 1) * 256 + t0);
            #pragma unroll
            for (int m = 0; m < 8; ++m) {
                acc[m][0] = __builtin_amdgcn_mfma_f32_16x16x32_bf16(a[m], b0, acc[m][0], 0, 0, 0);
                acc[m][1] = __builtin_amdgcn_mfma_f32_16x16x32_bf16(a[m], b1, acc[m][1], 0, 0, 0);
            }
        }

        // ---- exchange + combine epilogue, 4 steps of 1 m per direction ----
        // xbuf chunk: ((cn8*2 + dir)*2 + gate)*1024 + lane*16 ; dir0 = F,I  dir1 = G,O
        unsigned char* wr = xbuf + ((cn8 * 2 + rh) * 2) * 1024 + lane * 16;
        unsigned char* rd = xbuf + ((cn8 * 2 + (1 - rh)) * 2) * 1024 + lane * 16;
        #pragma unroll
        for (int mc = 0; mc < 4; ++mc) {
            __syncthreads();                       // xbuf free
            if (rh == 0) {                         // publish F,I of m = mc+4
                *(f32x4*)(wr)        = acc[mc + 4][0];
                *(f32x4*)(wr + 1024) = acc[mc + 4][1];
            } else {                               // publish G,O of m = mc
                *(f32x4*)(wr)        = acc[mc][0];
                *(f32x4*)(wr + 1024) = acc[mc][1];
            }
            __syncthreads();                       // xbuf ready
            f32x4 t0v = *(const f32x4*)(rd);
            f32x4 t1v = *(const f32x4*)(rd + 1024);
            int mo = rh ? (mc + 4) : mc;           // m this wave combines (uniform)
            #pragma unroll
            for (int r = 0; r < 4; ++r) {
                float F, I, G, O;
                if (rh == 0) { F = acc[mc][0][r];     I = acc[mc][1][r];     G = t0v[r]; O = t1v[r]; }
                else         { F = t0v[r]; I = t1v[r]; G = acc[mc + 4][0][r]; O = acc[mc + 4][1][r]; }
                float c = fsigmoid(F) + fsigmoid(I) * ftanh(G);
                float h = ftanh(c) * fsigmoid(O);
                int row = row0 + mo * 16 + lq * 4 + r;
                int o   = row * 512 + colj;
                out[o] = c;
                out[33554432 + o] = h;             // h plane at 65536*512
            }
        }
    }
}

extern "C" void kernel_launch(void* const* d_in, const int* in_sizes, int n_in,
                              void* d_out, int out_size, void* d_ws, size_t ws_size,
                              hipStream_t stream) {
    const float* xin = (const float*)d_in[0];
    const float* stm = (const float*)d_in[1];
    const float* Wf  = (const float*)d_in[2];
    const float* bf_ = (const float*)d_in[3];
    const float* Wi  = (const float*)d_in[4];
    const float* bi_ = (const float*)d_in[5];
    const float* Wg  = (const float*)d_in[6];
    const float* bg_ = (const float*)d_in[7];
    const float* Wo  = (const float*)d_in[8];
    const float* bo_ = (const float*)d_in[9];
    __bf16* Wp = (__bf16*)d_ws;                    // 2 MiB packed weights

    wpack<<<512, 256, 0, stream>>>(Wf, Wi, Wg, Wo, Wp);
    lstm_main<<<512, 1024, 0, stream>>>(xin, stm, Wp, bf_, bi_, bg_, bo_, (float*)d_out);
}